// Round 2
// baseline (148.930 us; speedup 1.0000x reference)
//
#include <hip/hip_runtime.h>
#include <hip/hip_bf16.h>
#include <stdint.h>

#define TEMPERATURE 0.07f

constexpr int NQ = 256;
constexpr int KQ = 8192;
constexpr int D  = 128;
constexpr int N  = NQ + 2 * KQ;   // 16640
constexpr int CS = 8;             // column splits
constexpr int BN = 64;            // columns per tile
constexpr int NT = N / BN;        // 260 column tiles
constexpr int RBS = N / 256;      // 65 row blocks

typedef short  s16x8  __attribute__((ext_vector_type(8)));
typedef float  f32x16 __attribute__((ext_vector_type(16)));

// ---- workspace layout (bytes) ----
constexpr size_t OFF_F32  = 0;                                  // float feat [N][D]
constexpr size_t OFF_BF16 = OFF_F32  + (size_t)N * D * 4;       // bf16 feat  [N][D]
constexpr size_t OFF_PART = OFF_BF16 + (size_t)N * D * 2;       // partials   [N][CS]
constexpr size_t OFF_LP   = OFF_PART + (size_t)N * CS * 4;      // label partials [128][2][128]
constexpr size_t OFF_S    = OFF_LP   + (size_t)128 * 2 * 128 * 4; // S [2][128]
constexpr size_t OFF_CNT  = OFF_S    + 2 * 128 * 4;             // counts [2] int
constexpr size_t OFF_BSUM = OFF_CNT  + 16;                      // blocksum [65]

// ---------------------------------------------------------------------------
// K1: build normalized feature matrix (f32 + bf16). One wave per row.
// ---------------------------------------------------------------------------
__global__ __launch_bounds__(256) void k_prep(const float* __restrict__ q,
                                              const float* __restrict__ ba,
                                              const float* __restrict__ nb,
                                              float* __restrict__ ff,
                                              unsigned short* __restrict__ fb) {
    int wid = threadIdx.x >> 6, lane = threadIdx.x & 63;
    int r = blockIdx.x * 4 + wid;
    const float* src = (r < NQ) ? (q + (size_t)r * D)
                     : (r < NQ + KQ) ? (ba + (size_t)(r - NQ) * D)
                     : (nb + (size_t)(r - NQ - KQ) * D);
    float2 v = *(const float2*)(src + lane * 2);
    float scale = 1.0f;
    if (r < NQ) {
        float ss = v.x * v.x + v.y * v.y;
        #pragma unroll
        for (int m = 1; m < 64; m <<= 1) ss += __shfl_xor(ss, m);
        float nrm = sqrtf(ss);
        nrm = fmaxf(nrm, 1e-12f);
        scale = 1.0f / nrm;
    }
    float a = v.x * scale, b = v.y * scale;
    *(float2*)(ff + (size_t)r * D + lane * 2) = make_float2(a, b);
    unsigned int ua = __float_as_uint(a);
    ua = (ua + 0x7fffu + ((ua >> 16) & 1u)) >> 16;
    unsigned int ub = __float_as_uint(b);
    ub = (ub + 0x7fffu + ((ub >> 16) & 1u)) >> 16;
    *(unsigned int*)(fb + (size_t)r * D + lane * 2) = ua | (ub << 16);
}

// ---------------------------------------------------------------------------
// K2a: per-label column sums, stage 1 (deterministic).  128 blocks x 130 rows.
// ---------------------------------------------------------------------------
__global__ __launch_bounds__(128) void k_lsum_a(const float* __restrict__ ff,
                                                const long long* __restrict__ tgt,
                                                float* __restrict__ lp) {
    int d = threadIdx.x;
    int r0 = blockIdx.x * 130;
    float p0 = 0.f, p1 = 0.f;
    for (int i = 0; i < 130; ++i) {
        int r = r0 + i;
        float v = ff[(size_t)r * D + d];
        int lab = (r < NQ) ? (int)tgt[r] : ((r < NQ + KQ) ? 1 : 0);
        if (lab) p1 += v; else p0 += v;
    }
    lp[((size_t)blockIdx.x * 2 + 0) * 128 + d] = p0;
    lp[((size_t)blockIdx.x * 2 + 1) * 128 + d] = p1;
}

// ---------------------------------------------------------------------------
// K2b: stage 2 reduction + label counts.
// ---------------------------------------------------------------------------
__global__ __launch_bounds__(128) void k_lsum_b(const float* __restrict__ lp,
                                                const long long* __restrict__ tgt,
                                                float* __restrict__ S,
                                                int* __restrict__ cnt) {
    int d = threadIdx.x;
    float s0 = 0.f, s1 = 0.f;
    for (int b = 0; b < 128; ++b) {
        s0 += lp[((size_t)b * 2 + 0) * 128 + d];
        s1 += lp[((size_t)b * 2 + 1) * 128 + d];
    }
    S[d]       = s0;   // label 0 sum
    S[128 + d] = s1;   // label 1 sum
    if (threadIdx.x < 64) {
        int c = 0;
        #pragma unroll
        for (int i = 0; i < 4; ++i) c += (int)tgt[threadIdx.x + 64 * i];
        #pragma unroll
        for (int m = 1; m < 64; m <<= 1) c += __shfl_xor(c, m);
        if (threadIdx.x == 0) { cnt[0] = (NQ - c) + KQ; cnt[1] = c + KQ; }
    }
}

// ---------------------------------------------------------------------------
// K3: main fused GEMM + exp row-sum.
//   Grid 65*8 = 520 blocks, 256 threads (4 waves x 64 rows).
//   Swapped MFMA: D[c][r] = colfeat . rowfeat^T so lane l owns row (l&31).
// ---------------------------------------------------------------------------
__global__ __launch_bounds__(256, 2) void k_main(const unsigned short* __restrict__ fb,
                                                 float* __restrict__ part) {
    __shared__ __align__(16) unsigned char lds[BN * 256];   // 64 cols x 256B (swizzled)
    int bid = blockIdx.x;
    int rb = bid / CS, cs = bid % CS;
    int lane = threadIdx.x & 63;
    int wid  = threadIdx.x >> 6;
    int l31 = lane & 31, lhi = lane >> 5;
    int r0 = rb * 256 + wid * 64;

    // row fragments (B operand), 64 rows per wave, K=128 -> 2 rsub x 8 ksteps
    s16x8 rf[2][8];
    #pragma unroll
    for (int rs = 0; rs < 2; ++rs)
        #pragma unroll
        for (int ks = 0; ks < 8; ++ks)
            rf[rs][ks] = *(const s16x8*)(fb + (size_t)(r0 + rs * 32 + l31) * D + ks * 16 + lhi * 8);

    const float sc = 1.4426950408889634f / TEMPERATURE;   // log2(e)/T ; shift = -sc
    float rsum[2] = {0.f, 0.f};
    int ntiles = (cs < (NT % CS)) ? (NT / CS + 1) : (NT / CS);

    for (int t = 0; t < ntiles; ++t) {
        int c0 = (cs + t * CS) * BN;
        __syncthreads();
        // stage 64x128 bf16 column tile into LDS, XOR-swizzled by (row&7)
        #pragma unroll
        for (int p = 0; p < 4; ++p) {
            int flat = p * 256 + threadIdx.x;
            int row = flat >> 4, ch = flat & 15;
            uint4 v = *(const uint4*)(fb + (size_t)(c0 + row) * D + ch * 8);
            *(uint4*)(lds + row * 256 + ((ch << 4) ^ ((row & 7) << 4))) = v;
        }
        __syncthreads();

        f32x16 acc[2][2];
        #pragma unroll
        for (int i = 0; i < 2; ++i)
            #pragma unroll
            for (int j = 0; j < 2; ++j)
                #pragma unroll
                for (int e = 0; e < 16; ++e) acc[i][j][e] = 0.f;

        #pragma unroll
        for (int ks = 0; ks < 8; ++ks) {
            #pragma unroll
            for (int cc = 0; cc < 2; ++cc) {
                int crow = cc * 32 + l31;
                s16x8 cf = *(const s16x8*)(lds + crow * 256 +
                               ((ks * 32 + lhi * 16) ^ ((crow & 7) << 4)));
                acc[cc][0] = __builtin_amdgcn_mfma_f32_32x32x16_bf16(cf, rf[0][ks], acc[cc][0], 0, 0, 0);
                acc[cc][1] = __builtin_amdgcn_mfma_f32_32x32x16_bf16(cf, rf[1][ks], acc[cc][1], 0, 0, 0);
            }
        }

        // epilogue: e = exp2(sim*log2e/T - log2e/T) = exp(sim/T - 1/T), mask diagonal
        #pragma unroll
        for (int cc = 0; cc < 2; ++cc) {
            #pragma unroll
            for (int rs = 0; rs < 2; ++rs) {
                int rg = r0 + rs * 32 + l31;
                float p = 0.f;
                #pragma unroll
                for (int g = 0; g < 16; ++g) {
                    int cg = c0 + cc * 32 + (g & 3) + ((g >> 2) << 3) + (lhi << 2);
                    float e = __builtin_amdgcn_exp2f(acc[cc][rs][g] * sc - sc);
                    p += (cg == rg) ? 0.f : e;
                }
                rsum[rs] += p;
            }
        }
    }
    // combine the two c-halves (lane and lane^32 hold same row, different cols)
    rsum[0] += __shfl_xor(rsum[0], 32);
    rsum[1] += __shfl_xor(rsum[1], 32);
    if (lane < 32) {
        part[(size_t)(r0 + lane) * CS + cs]      = rsum[0];
        part[(size_t)(r0 + 32 + lane) * CS + cs] = rsum[1];
    }
}

// ---------------------------------------------------------------------------
// K4: per-row finalize: LSE + positive term; block-reduce partial loss.
// ---------------------------------------------------------------------------
__global__ __launch_bounds__(256) void k_rowfin(const float* __restrict__ part,
                                                const float* __restrict__ ff,
                                                const float* __restrict__ S,
                                                const int* __restrict__ cnt,
                                                const long long* __restrict__ tgt,
                                                float* __restrict__ bsum) {
    __shared__ float sS[256];
    __shared__ float red[256];
    sS[threadIdx.x] = S[threadIdx.x];
    __syncthreads();
    int r = blockIdx.x * 256 + threadIdx.x;
    float se = 0.f;
    #pragma unroll
    for (int c = 0; c < CS; ++c) se += part[(size_t)r * CS + c];
    float lse = logf(se) + 1.0f / TEMPERATURE;
    int lab = (r < NQ) ? (int)tgt[r] : ((r < NQ + KQ) ? 1 : 0);
    const float4* frow = (const float4*)(ff + (size_t)r * D);
    const float4* srow = (const float4*)(sS + lab * 128);
    float dS = 0.f, dself = 0.f;
    #pragma unroll
    for (int i = 0; i < 32; ++i) {
        float4 f = frow[i];
        float4 s = srow[i];
        dS    += f.x * s.x + f.y * s.y + f.z * s.z + f.w * s.w;
        dself += f.x * f.x + f.y * f.y + f.z * f.z + f.w * f.w;
    }
    float P = (float)(cnt[lab] - 1);
    float mlpp = (dS - dself) / (TEMPERATURE * P) - lse;
    red[threadIdx.x] = mlpp;
    __syncthreads();
    for (int s2 = 128; s2 > 0; s2 >>= 1) {
        if (threadIdx.x < s2) red[threadIdx.x] += red[threadIdx.x + s2];
        __syncthreads();
    }
    if (threadIdx.x == 0) bsum[blockIdx.x] = red[0];
}

// ---------------------------------------------------------------------------
// K5: final scalar.
// ---------------------------------------------------------------------------
__global__ __launch_bounds__(64) void k_final(const float* __restrict__ bsum,
                                              float* __restrict__ out) {
    float s = bsum[threadIdx.x];                 // RBS=65 > 64, lanes 0..63 valid
    if (threadIdx.x == 0) s += bsum[64];
    #pragma unroll
    for (int m = 1; m < 64; m <<= 1) s += __shfl_xor(s, m);
    if (threadIdx.x == 0) out[0] = -s / (float)N;
}

extern "C" void kernel_launch(void* const* d_in, const int* in_sizes, int n_in,
                              void* d_out, int out_size, void* d_ws, size_t ws_size,
                              hipStream_t stream) {
    const float* q       = (const float*)d_in[0];
    const float* ba      = (const float*)d_in[1];
    const float* nb      = (const float*)d_in[2];
    const long long* tgt = (const long long*)d_in[3];
    char* ws = (char*)d_ws;
    float*          ff   = (float*)(ws + OFF_F32);
    unsigned short* fb   = (unsigned short*)(ws + OFF_BF16);
    float*          part = (float*)(ws + OFF_PART);
    float*          lp   = (float*)(ws + OFF_LP);
    float*          S    = (float*)(ws + OFF_S);
    int*            cnt  = (int*)(ws + OFF_CNT);
    float*          bsum = (float*)(ws + OFF_BSUM);

    k_prep  <<<N / 4, 256, 0, stream>>>(q, ba, nb, ff, fb);
    k_lsum_a<<<128,   128, 0, stream>>>(ff, tgt, lp);
    k_lsum_b<<<1,     128, 0, stream>>>(lp, tgt, S, cnt);
    k_main  <<<RBS * CS, 256, 0, stream>>>(fb, part);
    k_rowfin<<<RBS,   256, 0, stream>>>(part, ff, S, cnt, tgt, bsum);
    k_final <<<1,      64, 0, stream>>>(bsum, (float*)d_out);
}

// Round 3
// 135.956 us; speedup vs baseline: 1.0954x; 1.0954x over previous
//
#include <hip/hip_runtime.h>
#include <hip/hip_bf16.h>
#include <stdint.h>

#define TEMPERATURE 0.07f

constexpr int NQ = 256;
constexpr int KQ = 8192;
constexpr int D  = 128;
constexpr int N  = NQ + 2 * KQ;   // 16640
constexpr int CS = 32;            // column splits (2080 blocks: load balance + occupancy)
constexpr int BN = 64;            // columns per tile
constexpr int NT = N / BN;        // 260 column tiles
constexpr int RBS = N / 256;      // 65 row blocks

typedef short  s16x8  __attribute__((ext_vector_type(8)));
typedef float  f32x16 __attribute__((ext_vector_type(16)));

// ---- workspace layout (bytes) ----
constexpr size_t OFF_F32  = 0;                                    // float feat [N][D]
constexpr size_t OFF_BF16 = OFF_F32  + (size_t)N * D * 4;         // bf16 feat  [N][D]
constexpr size_t OFF_PART = OFF_BF16 + (size_t)N * D * 2;         // partials   [N][CS]
constexpr size_t OFF_LP   = OFF_PART + (size_t)N * CS * 4;        // label partials [260][2][128]
constexpr size_t OFF_S    = OFF_LP   + (size_t)260 * 2 * 128 * 4; // S [2][128]
constexpr size_t OFF_CNT  = OFF_S    + 2 * 128 * 4;               // counts [2] int
constexpr size_t OFF_BSUM = OFF_CNT  + 16;                        // blocksum [65]

// ---------------------------------------------------------------------------
// K1: build normalized feature matrix (f32 + bf16). One wave per row.
// ---------------------------------------------------------------------------
__global__ __launch_bounds__(256) void k_prep(const float* __restrict__ q,
                                              const float* __restrict__ ba,
                                              const float* __restrict__ nb,
                                              float* __restrict__ ff,
                                              unsigned short* __restrict__ fb) {
    int wid = threadIdx.x >> 6, lane = threadIdx.x & 63;
    int r = blockIdx.x * 4 + wid;
    const float* src = (r < NQ) ? (q + (size_t)r * D)
                     : (r < NQ + KQ) ? (ba + (size_t)(r - NQ) * D)
                     : (nb + (size_t)(r - NQ - KQ) * D);
    float2 v = *(const float2*)(src + lane * 2);
    float scale = 1.0f;
    if (r < NQ) {
        float ss = v.x * v.x + v.y * v.y;
        #pragma unroll
        for (int m = 1; m < 64; m <<= 1) ss += __shfl_xor(ss, m);
        float nrm = sqrtf(ss);
        nrm = fmaxf(nrm, 1e-12f);
        scale = 1.0f / nrm;
    }
    float a = v.x * scale, b = v.y * scale;
    *(float2*)(ff + (size_t)r * D + lane * 2) = make_float2(a, b);
    unsigned int ua = __float_as_uint(a);
    ua = (ua + 0x7fffu + ((ua >> 16) & 1u)) >> 16;
    unsigned int ub = __float_as_uint(b);
    ub = (ub + 0x7fffu + ((ub >> 16) & 1u)) >> 16;
    *(unsigned int*)(fb + (size_t)r * D + lane * 2) = ua | (ub << 16);
}

// ---------------------------------------------------------------------------
// K2a: per-label column sums, stage 1 (deterministic). 260 blocks x 64 rows.
// ---------------------------------------------------------------------------
__global__ __launch_bounds__(128) void k_lsum_a(const float* __restrict__ ff,
                                                const long long* __restrict__ tgt,
                                                float* __restrict__ lp) {
    int d = threadIdx.x;
    int r0 = blockIdx.x * 64;
    float p0 = 0.f, p1 = 0.f;
    for (int i = 0; i < 64; ++i) {
        int r = r0 + i;
        float v = ff[(size_t)r * D + d];
        int lab = (r < NQ) ? (int)tgt[r] : ((r < NQ + KQ) ? 1 : 0);
        if (lab) p1 += v; else p0 += v;
    }
    lp[((size_t)blockIdx.x * 2 + 0) * 128 + d] = p0;
    lp[((size_t)blockIdx.x * 2 + 1) * 128 + d] = p1;
}

// ---------------------------------------------------------------------------
// K2b: stage 2 reduction + label counts.
// ---------------------------------------------------------------------------
__global__ __launch_bounds__(128) void k_lsum_b(const float* __restrict__ lp,
                                                const long long* __restrict__ tgt,
                                                float* __restrict__ S,
                                                int* __restrict__ cnt) {
    int d = threadIdx.x;
    float s0 = 0.f, s1 = 0.f;
    for (int b = 0; b < 260; ++b) {
        s0 += lp[((size_t)b * 2 + 0) * 128 + d];
        s1 += lp[((size_t)b * 2 + 1) * 128 + d];
    }
    S[d]       = s0;   // label 0 sum
    S[128 + d] = s1;   // label 1 sum
    if (threadIdx.x < 64) {
        int c = 0;
        #pragma unroll
        for (int i = 0; i < 4; ++i) c += (int)tgt[threadIdx.x + 64 * i];
        #pragma unroll
        for (int m = 1; m < 64; m <<= 1) c += __shfl_xor(c, m);
        if (threadIdx.x == 0) { cnt[0] = (NQ - c) + KQ; cnt[1] = c + KQ; }
    }
}

// ---------------------------------------------------------------------------
// K3: main fused GEMM + exp row-sum.
//   Grid 65*32 = 2080 blocks, 256 threads (4 waves x 64 rows).
//   Swapped MFMA: D[c][r] = colfeat . rowfeat^T so lane l owns row (l&31).
//   Diagonal masking only on the (at most one) tile per block that hits it.
// ---------------------------------------------------------------------------
__global__ __launch_bounds__(256, 2) void k_main(const unsigned short* __restrict__ fb,
                                                 float* __restrict__ part) {
    __shared__ __align__(16) unsigned char lds[BN * 256];   // 64 cols x 256B (swizzled)
    int bid = blockIdx.x;
    int rb = bid / CS, cs = bid % CS;
    int lane = threadIdx.x & 63;
    int wid  = threadIdx.x >> 6;
    int l31 = lane & 31, lhi = lane >> 5;
    int r0 = rb * 256 + wid * 64;

    // row fragments (B operand), 64 rows per wave, K=128 -> 2 rsub x 8 ksteps
    s16x8 rf[2][8];
    #pragma unroll
    for (int rs = 0; rs < 2; ++rs)
        #pragma unroll
        for (int ks = 0; ks < 8; ++ks)
            rf[rs][ks] = *(const s16x8*)(fb + (size_t)(r0 + rs * 32 + l31) * D + ks * 16 + lhi * 8);

    const float sc = 1.4426950408889634f / TEMPERATURE;   // log2(e)/T ; shift = -sc
    float rsum[2] = {0.f, 0.f};
    int ntiles = (cs < (NT % CS)) ? (NT / CS + 1) : (NT / CS);

    for (int t = 0; t < ntiles; ++t) {
        int ct = cs + t * CS;
        int c0 = ct * BN;
        __syncthreads();
        // stage 64x128 bf16 column tile into LDS, XOR-swizzled by (row&15)
        #pragma unroll
        for (int p = 0; p < 4; ++p) {
            int flat = p * 256 + threadIdx.x;
            int row = flat >> 4, ch = flat & 15;
            uint4 v = *(const uint4*)(fb + (size_t)(c0 + row) * D + ch * 8);
            *(uint4*)(lds + row * 256 + ((ch << 4) ^ ((row & 15) << 4))) = v;
        }
        __syncthreads();

        f32x16 acc[2][2];
        #pragma unroll
        for (int i = 0; i < 2; ++i)
            #pragma unroll
            for (int j = 0; j < 2; ++j)
                #pragma unroll
                for (int e = 0; e < 16; ++e) acc[i][j][e] = 0.f;

        #pragma unroll
        for (int ks = 0; ks < 8; ++ks) {
            #pragma unroll
            for (int cc = 0; cc < 2; ++cc) {
                int crow = cc * 32 + l31;
                s16x8 cf = *(const s16x8*)(lds + crow * 256 +
                               ((ks * 32 + lhi * 16) ^ ((crow & 15) << 4)));
                acc[cc][0] = __builtin_amdgcn_mfma_f32_32x32x16_bf16(cf, rf[0][ks], acc[cc][0], 0, 0, 0);
                acc[cc][1] = __builtin_amdgcn_mfma_f32_32x32x16_bf16(cf, rf[1][ks], acc[cc][1], 0, 0, 0);
            }
        }

        // epilogue: e = exp2(sim*log2e/T - log2e/T) = exp(sim/T - 1/T)
        if ((unsigned)(ct - rb * 4) < 4u) {
            // diagonal tile: mask self-similarity per element
            #pragma unroll
            for (int cc = 0; cc < 2; ++cc) {
                #pragma unroll
                for (int rs = 0; rs < 2; ++rs) {
                    int rg = r0 + rs * 32 + l31;
                    float p = 0.f;
                    #pragma unroll
                    for (int g = 0; g < 16; ++g) {
                        int cg = c0 + cc * 32 + (g & 3) + ((g >> 2) << 3) + (lhi << 2);
                        float e = __builtin_amdgcn_exp2f(acc[cc][rs][g] * sc - sc);
                        p += (cg == rg) ? 0.f : e;
                    }
                    rsum[rs] += p;
                }
            }
        } else {
            #pragma unroll
            for (int cc = 0; cc < 2; ++cc) {
                #pragma unroll
                for (int rs = 0; rs < 2; ++rs) {
                    float p = 0.f;
                    #pragma unroll
                    for (int g = 0; g < 16; ++g)
                        p += __builtin_amdgcn_exp2f(acc[cc][rs][g] * sc - sc);
                    rsum[rs] += p;
                }
            }
        }
    }
    // combine the two c-halves (lane and lane^32 hold same row, different cols)
    rsum[0] += __shfl_xor(rsum[0], 32);
    rsum[1] += __shfl_xor(rsum[1], 32);
    if (lane < 32) {
        part[(size_t)(r0 + lane) * CS + cs]      = rsum[0];
        part[(size_t)(r0 + 32 + lane) * CS + cs] = rsum[1];
    }
}

// ---------------------------------------------------------------------------
// K4: per-row finalize: LSE + positive term; block-reduce partial loss.
// ---------------------------------------------------------------------------
__global__ __launch_bounds__(256) void k_rowfin(const float* __restrict__ part,
                                                const float* __restrict__ ff,
                                                const float* __restrict__ S,
                                                const int* __restrict__ cnt,
                                                const long long* __restrict__ tgt,
                                                float* __restrict__ bsum) {
    __shared__ float sS[256];
    __shared__ float red[256];
    sS[threadIdx.x] = S[threadIdx.x];
    __syncthreads();
    int r = blockIdx.x * 256 + threadIdx.x;
    float se = 0.f;
    #pragma unroll
    for (int c = 0; c < CS; ++c) se += part[(size_t)r * CS + c];
    float lse = logf(se) + 1.0f / TEMPERATURE;
    int lab = (r < NQ) ? (int)tgt[r] : ((r < NQ + KQ) ? 1 : 0);
    const float4* frow = (const float4*)(ff + (size_t)r * D);
    const float4* srow = (const float4*)(sS + lab * 128);
    float dS = 0.f, dself = 0.f;
    #pragma unroll
    for (int i = 0; i < 32; ++i) {
        float4 f = frow[i];
        float4 s = srow[i];
        dS    += f.x * s.x + f.y * s.y + f.z * s.z + f.w * s.w;
        dself += f.x * f.x + f.y * f.y + f.z * f.z + f.w * f.w;
    }
    float P = (float)(cnt[lab] - 1);
    float mlpp = (dS - dself) / (TEMPERATURE * P) - lse;
    red[threadIdx.x] = mlpp;
    __syncthreads();
    for (int s2 = 128; s2 > 0; s2 >>= 1) {
        if (threadIdx.x < s2) red[threadIdx.x] += red[threadIdx.x + s2];
        __syncthreads();
    }
    if (threadIdx.x == 0) bsum[blockIdx.x] = red[0];
}

// ---------------------------------------------------------------------------
// K5: final scalar.
// ---------------------------------------------------------------------------
__global__ __launch_bounds__(64) void k_final(const float* __restrict__ bsum,
                                              float* __restrict__ out) {
    float s = bsum[threadIdx.x];                 // RBS=65 > 64, lanes 0..63 valid
    if (threadIdx.x == 0) s += bsum[64];
    #pragma unroll
    for (int m = 1; m < 64; m <<= 1) s += __shfl_xor(s, m);
    if (threadIdx.x == 0) out[0] = -s / (float)N;
}

extern "C" void kernel_launch(void* const* d_in, const int* in_sizes, int n_in,
                              void* d_out, int out_size, void* d_ws, size_t ws_size,
                              hipStream_t stream) {
    const float* q       = (const float*)d_in[0];
    const float* ba      = (const float*)d_in[1];
    const float* nb      = (const float*)d_in[2];
    const long long* tgt = (const long long*)d_in[3];
    char* ws = (char*)d_ws;
    float*          ff   = (float*)(ws + OFF_F32);
    unsigned short* fb   = (unsigned short*)(ws + OFF_BF16);
    float*          part = (float*)(ws + OFF_PART);
    float*          lp   = (float*)(ws + OFF_LP);
    float*          S    = (float*)(ws + OFF_S);
    int*            cnt  = (int*)(ws + OFF_CNT);
    float*          bsum = (float*)(ws + OFF_BSUM);

    k_prep  <<<N / 4, 256, 0, stream>>>(q, ba, nb, ff, fb);
    k_lsum_a<<<260,   128, 0, stream>>>(ff, tgt, lp);
    k_lsum_b<<<1,     128, 0, stream>>>(lp, tgt, S, cnt);
    k_main  <<<RBS * CS, 256, 0, stream>>>(fb, part);
    k_rowfin<<<RBS,   256, 0, stream>>>(part, ff, S, cnt, tgt, bsum);
    k_final <<<1,      64, 0, stream>>>(bsum, (float*)d_out);
}